// Round 11
// baseline (73.163 us; speedup 1.0000x reference)
//
#include <hip/hip_runtime.h>

typedef _Float16 half4_t __attribute__((ext_vector_type(4)));
typedef _Float16 half8_t __attribute__((ext_vector_type(8)));
typedef float    f32x4  __attribute__((ext_vector_type(4)));

#define FS 136           // f16 stride for sTmp rows (136 halfs = 272 B)
#define EPS_V 1e-8f
#define MARGIN 6.0f      // exp(-36/4)=1.2e-4 pre-normalization tail: negligible

__device__ __forceinline__ half8_t cvt8(f32x4 a, f32x4 b) {
    half8_t h;
    h[0] = (_Float16)a.x; h[1] = (_Float16)a.y; h[2] = (_Float16)a.z; h[3] = (_Float16)a.w;
    h[4] = (_Float16)b.x; h[5] = (_Float16)b.y; h[6] = (_Float16)b.z; h[7] = (_Float16)b.w;
    return h;
}

// out[b,c,m,n] = gamma * sum_h Fy[m,h] * sum_w img[h,w] * Fx[n,w]
// One block per b handles BOTH channels; exact windowed reads; image reads are
// NONTEMPORAL (read-once 512MB stream > 256MB L3 -> bypass cache insertion).
__global__ __launch_bounds__(256) void glimpse_kernel(
    const float* __restrict__ vec,   // (4096, 3)
    const float* __restrict__ img,   // (4096, 2, 128, 128)
    float* __restrict__ out)         // (4096, 2, 12, 12)
{
    const int b    = blockIdx.x;
    const int t    = threadIdx.x;
    const int lane = t & 63;
    const int wv   = t >> 6;
    const int fr   = lane & 15;      // fragment row/col index
    const int fq   = lane >> 4;      // fragment k-quad (0..3)

    __shared__ __align__(16) _Float16 sTmp[2][16 * FS];  // per-channel tmp[n][h']
    __shared__ __align__(16) float    sOut[2][144];

    const float gx_ = vec[b * 3 + 0];
    const float gy_ = vec[b * 3 + 1];
    const float ld  = vec[b * 3 + 2];
    const float delta = 4.0f * (ld + 1.0f);
    const float gx = 64.0f * (gx_ + 1.0f);
    const float gy = 64.0f * (gy_ + 1.0f);

    // ---- active windows ----
    int c0 = (int)floorf(gx - 6.5f * delta - MARGIN);
    c0 = (c0 < 0 ? 0 : c0) & ~7;                     // 8-float aligned
    int c1 = (int)ceilf(gx + 4.5f * delta + MARGIN) + 1;
    c1 = c1 > 128 ? 128 : c1;
    const int kn = (c1 - c0 + 31) >> 5;              // col K-tiles, 1..4

    int r0 = (int)floorf(gy - 6.5f * delta - MARGIN);
    r0 = r0 < 0 ? 0 : r0;
    int r1 = (int)ceilf(gy + 4.5f * delta + MARGIN) + 1;
    r1 = r1 > 128 ? 128 : r1;
    const int rn   = r1 - r0;
    const int k2n  = (rn + 31) >> 5;                 // phase-2 K-tiles, 1..4
    const int mtp  = 2 * k2n;                        // padded 16-row tiles in sTmp
    const int mt16 = (rn + 15) >> 4;                 // tiles containing real rows

    // ---- Fx fragments (B operand): exact-zero for w >= c1 or n >= 12 ----
    half8_t bfrag[4];
    {
        const float mux = gx + ((float)fr - 6.5f) * delta;
        float s = 0.f;
        #pragma unroll
        for (int kt = 0; kt < 4; ++kt) if (kt < kn) {
            #pragma unroll
            for (int j = 0; j < 8; ++j) {
                int w = c0 + 32 * kt + 8 * fq + j;
                float d = (float)w - mux;
                s += (w < c1) ? __expf(-d * d * 0.25f) : 0.f;
            }
        }
        s += __shfl_xor(s, 16);
        s += __shfl_xor(s, 32);
        const float inv = 1.0f / fmaxf(s, EPS_V);
        #pragma unroll
        for (int kt = 0; kt < 4; ++kt) {
            bfrag[kt] = half8_t{};
            if (kt < kn && fr < 12) {
                #pragma unroll
                for (int j = 0; j < 8; ++j) {
                    int w = c0 + 32 * kt + 8 * fq + j;
                    float d = (float)w - mux;
                    bfrag[kt][j] = (_Float16)((w < c1) ? __expf(-d * d * 0.25f) * inv : 0.f);
                }
            }
        }
    }

    // ---- phase 1: tmp[ch] = img_window[ch] * Fx^T for both channels ----
    const float* gb0 = img + (size_t)b * 32768;
    #pragma unroll
    for (int ch = 0; ch < 2; ++ch) {
        const float* gb = gb0 + ch * 16384;
        #pragma unroll
        for (int ti = 0; ti < 2; ++ti) {
            const int tl = wv + 4 * ti;              // 16-row tile index (wave-uniform)
            if (tl < mtp) {
                half4_t dst = half4_t{};
                if (tl < mt16) {
                    const int rowg = r0 + 16 * tl + fr;
                    const bool rok = rowg < r1;
                    const float* rp = gb + rowg * 128;
                    f32x4 acc = {0.f, 0.f, 0.f, 0.f};
                    #pragma unroll
                    for (int kt = 0; kt < 4; ++kt) if (kt < kn) {
                        const int col = c0 + 32 * kt + 8 * fq;   // multiple of 8
                        half8_t a0 = half8_t{};                   // wave-wide zero init
                        if (rok && col < c1) {                    // predicated nt load
                            f32x4 lo = __builtin_nontemporal_load(
                                reinterpret_cast<const f32x4*>(rp + col));
                            f32x4 hi = __builtin_nontemporal_load(
                                reinterpret_cast<const f32x4*>(rp + col + 4));
                            a0 = cvt8(lo, hi);
                        }
                        acc = __builtin_amdgcn_mfma_f32_16x16x32_f16(a0, bfrag[kt], acc, 0, 0, 0);
                    }
                    #pragma unroll
                    for (int r = 0; r < 4; ++r) dst[r] = (_Float16)acc[r];
                }
                // D: lane holds tmp[h' = 16*tl + 4*fq + r][n = fr]; zero-fill pad tiles
                *reinterpret_cast<half4_t*>(&sTmp[ch][fr * FS + 16 * tl + 4 * fq]) = dst;
            }
        }
    }

    asm volatile("s_waitcnt lgkmcnt(0)" ::: "memory");
    __builtin_amdgcn_s_barrier();

    // ---- phase 2: out[ch] = Fy' * tmp[ch]; wave 0 -> ch 0, wave 1 -> ch 1 ----
    if (wv < 2) {
        half8_t afy[4];
        {
            const float muy = gy + ((float)fr - 6.5f) * delta;
            float s = 0.f;
            #pragma unroll
            for (int kt = 0; kt < 4; ++kt) if (kt < k2n) {
                #pragma unroll
                for (int j = 0; j < 8; ++j) {
                    int h = r0 + 32 * kt + 8 * fq + j;
                    float d = (float)h - muy;
                    s += (h < r1) ? __expf(-d * d * 0.25f) : 0.f;
                }
            }
            s += __shfl_xor(s, 16);
            s += __shfl_xor(s, 32);
            const float inv = 4.0f / fmaxf(s, EPS_V);    // gamma folded
            #pragma unroll
            for (int kt = 0; kt < 4; ++kt) {
                afy[kt] = half8_t{};
                if (kt < k2n && fr < 12) {
                    #pragma unroll
                    for (int j = 0; j < 8; ++j) {
                        int h = r0 + 32 * kt + 8 * fq + j;
                        float d = (float)h - muy;
                        afy[kt][j] = (_Float16)((h < r1) ? __expf(-d * d * 0.25f) * inv : 0.f);
                    }
                }
            }
        }
        f32x4 acc = {0.f, 0.f, 0.f, 0.f};
        #pragma unroll
        for (int kt = 0; kt < 4; ++kt) if (kt < k2n) {
            half8_t bb = *reinterpret_cast<const half8_t*>(&sTmp[wv][fr * FS + 32 * kt + 8 * fq]);
            acc = __builtin_amdgcn_mfma_f32_16x16x32_f16(afy[kt], bb, acc, 0, 0, 0);
        }
        // C[m = 4*fq + r][n = fr] -> LDS bounce -> coalesced float4 store
        if (fr < 12 && fq < 3) {
            #pragma unroll
            for (int r = 0; r < 4; ++r)
                sOut[wv][(fq * 4 + r) * 12 + fr] = acc[r];
        }
        asm volatile("s_waitcnt lgkmcnt(0)" ::: "memory");
        __builtin_amdgcn_sched_barrier(0);
        if (lane < 36) {
            float4 o = *reinterpret_cast<const float4*>(&sOut[wv][lane * 4]);
            *reinterpret_cast<float4*>(out + (size_t)(2 * b + wv) * 144 + lane * 4) = o;
        }
    }
}

extern "C" void kernel_launch(void* const* d_in, const int* in_sizes, int n_in,
                              void* d_out, int out_size, void* d_ws, size_t ws_size,
                              hipStream_t stream) {
    const float* vec = (const float*)d_in[0];  // (4096,3) f32
    const float* img = (const float*)d_in[1];  // (4096,2,128,128) f32
    float* out = (float*)d_out;                // (4096,2,12,12) f32
    (void)in_sizes; (void)n_in; (void)out_size; (void)d_ws; (void)ws_size;

    glimpse_kernel<<<4096, 256, 0, stream>>>(vec, img, out);
}

// Round 12
// 45.531 us; speedup vs baseline: 1.6069x; 1.6069x over previous
//
#include <hip/hip_runtime.h>

typedef _Float16 half4_t __attribute__((ext_vector_type(4)));
typedef _Float16 half8_t __attribute__((ext_vector_type(8)));
typedef float    f32x4  __attribute__((ext_vector_type(4)));

#define FS 136           // f16 stride for sTmp rows (136 halfs = 272 B)
#define EPS_V 1e-8f
#define MARGIN 6.0f      // exp(-36/4)=1.2e-4 pre-normalization tail: negligible

__device__ __forceinline__ half8_t cvt8(float4 a, float4 b) {
    half8_t h;
    h[0] = (_Float16)a.x; h[1] = (_Float16)a.y; h[2] = (_Float16)a.z; h[3] = (_Float16)a.w;
    h[4] = (_Float16)b.x; h[5] = (_Float16)b.y; h[6] = (_Float16)b.z; h[7] = (_Float16)b.w;
    return h;
}

// out[b,c,m,n] = gamma * sum_h Fy[m,h] * sum_w img[h,w] * Fx[n,w]
// One block per b handles BOTH channels: filters/window computed once,
// exact windowed reads (row-exact, 8-col-granular), MFMA contraction.
// NOTE: loads must stay CACHED — nontemporal probe (R10/R11) cost +60%:
// L2 merges the overlapping 32B fragment loads into single line fetches.
__global__ __launch_bounds__(256) void glimpse_kernel(
    const float* __restrict__ vec,   // (4096, 3)
    const float* __restrict__ img,   // (4096, 2, 128, 128)
    float* __restrict__ out)         // (4096, 2, 12, 12)
{
    const int b    = blockIdx.x;
    const int t    = threadIdx.x;
    const int lane = t & 63;
    const int wv   = t >> 6;
    const int fr   = lane & 15;      // fragment row/col index
    const int fq   = lane >> 4;      // fragment k-quad (0..3)

    __shared__ __align__(16) _Float16 sTmp[2][16 * FS];  // per-channel tmp[n][h']
    __shared__ __align__(16) float    sOut[2][144];

    const float gx_ = vec[b * 3 + 0];
    const float gy_ = vec[b * 3 + 1];
    const float ld  = vec[b * 3 + 2];
    const float delta = 4.0f * (ld + 1.0f);
    const float gx = 64.0f * (gx_ + 1.0f);
    const float gy = 64.0f * (gy_ + 1.0f);

    // ---- active windows ----
    int c0 = (int)floorf(gx - 6.5f * delta - MARGIN);
    c0 = (c0 < 0 ? 0 : c0) & ~7;                     // 8-float aligned
    int c1 = (int)ceilf(gx + 4.5f * delta + MARGIN) + 1;
    c1 = c1 > 128 ? 128 : c1;
    const int kn = (c1 - c0 + 31) >> 5;              // col K-tiles, 1..4

    int r0 = (int)floorf(gy - 6.5f * delta - MARGIN);
    r0 = r0 < 0 ? 0 : r0;
    int r1 = (int)ceilf(gy + 4.5f * delta + MARGIN) + 1;
    r1 = r1 > 128 ? 128 : r1;
    const int rn   = r1 - r0;
    const int k2n  = (rn + 31) >> 5;                 // phase-2 K-tiles, 1..4
    const int mtp  = 2 * k2n;                        // padded 16-row tiles in sTmp
    const int mt16 = (rn + 15) >> 4;                 // tiles containing real rows

    // ---- Fx fragments (B operand): exact-zero for w >= c1 or n >= 12 ----
    half8_t bfrag[4];
    {
        const float mux = gx + ((float)fr - 6.5f) * delta;
        float s = 0.f;
        #pragma unroll
        for (int kt = 0; kt < 4; ++kt) if (kt < kn) {
            #pragma unroll
            for (int j = 0; j < 8; ++j) {
                int w = c0 + 32 * kt + 8 * fq + j;
                float d = (float)w - mux;
                s += (w < c1) ? __expf(-d * d * 0.25f) : 0.f;
            }
        }
        s += __shfl_xor(s, 16);
        s += __shfl_xor(s, 32);
        const float inv = 1.0f / fmaxf(s, EPS_V);
        #pragma unroll
        for (int kt = 0; kt < 4; ++kt) {
            bfrag[kt] = half8_t{};
            if (kt < kn && fr < 12) {
                #pragma unroll
                for (int j = 0; j < 8; ++j) {
                    int w = c0 + 32 * kt + 8 * fq + j;
                    float d = (float)w - mux;
                    bfrag[kt][j] = (_Float16)((w < c1) ? __expf(-d * d * 0.25f) * inv : 0.f);
                }
            }
        }
    }

    // ---- phase 1: tmp[ch] = img_window[ch] * Fx^T for both channels ----
    const float* gb0 = img + (size_t)b * 32768;
    #pragma unroll
    for (int ch = 0; ch < 2; ++ch) {
        const float* gb = gb0 + ch * 16384;
        #pragma unroll
        for (int ti = 0; ti < 2; ++ti) {
            const int tl = wv + 4 * ti;              // 16-row tile index (wave-uniform)
            if (tl < mtp) {
                half4_t dst = half4_t{};
                if (tl < mt16) {
                    const int rowg = r0 + 16 * tl + fr;
                    const bool rok = rowg < r1;
                    const float* rp = gb + rowg * 128;
                    f32x4 acc = {0.f, 0.f, 0.f, 0.f};
                    #pragma unroll
                    for (int kt = 0; kt < 4; ++kt) if (kt < kn) {
                        const int col = c0 + 32 * kt + 8 * fq;   // multiple of 8
                        half8_t a0 = half8_t{};                   // wave-wide zero init
                        if (rok && col < c1) {                    // predicated load
                            float4 lo = *reinterpret_cast<const float4*>(rp + col);
                            float4 hi = *reinterpret_cast<const float4*>(rp + col + 4);
                            a0 = cvt8(lo, hi);
                        }
                        acc = __builtin_amdgcn_mfma_f32_16x16x32_f16(a0, bfrag[kt], acc, 0, 0, 0);
                    }
                    #pragma unroll
                    for (int r = 0; r < 4; ++r) dst[r] = (_Float16)acc[r];
                }
                // D: lane holds tmp[h' = 16*tl + 4*fq + r][n = fr]; zero-fill pad tiles
                *reinterpret_cast<half4_t*>(&sTmp[ch][fr * FS + 16 * tl + 4 * fq]) = dst;
            }
        }
    }

    asm volatile("s_waitcnt lgkmcnt(0)" ::: "memory");
    __builtin_amdgcn_s_barrier();

    // ---- phase 2: out[ch] = Fy' * tmp[ch]; wave 0 -> ch 0, wave 1 -> ch 1 ----
    if (wv < 2) {
        half8_t afy[4];
        {
            const float muy = gy + ((float)fr - 6.5f) * delta;
            float s = 0.f;
            #pragma unroll
            for (int kt = 0; kt < 4; ++kt) if (kt < k2n) {
                #pragma unroll
                for (int j = 0; j < 8; ++j) {
                    int h = r0 + 32 * kt + 8 * fq + j;
                    float d = (float)h - muy;
                    s += (h < r1) ? __expf(-d * d * 0.25f) : 0.f;
                }
            }
            s += __shfl_xor(s, 16);
            s += __shfl_xor(s, 32);
            const float inv = 4.0f / fmaxf(s, EPS_V);    // gamma folded
            #pragma unroll
            for (int kt = 0; kt < 4; ++kt) {
                afy[kt] = half8_t{};
                if (kt < k2n && fr < 12) {
                    #pragma unroll
                    for (int j = 0; j < 8; ++j) {
                        int h = r0 + 32 * kt + 8 * fq + j;
                        float d = (float)h - muy;
                        afy[kt][j] = (_Float16)((h < r1) ? __expf(-d * d * 0.25f) * inv : 0.f);
                    }
                }
            }
        }
        f32x4 acc = {0.f, 0.f, 0.f, 0.f};
        #pragma unroll
        for (int kt = 0; kt < 4; ++kt) if (kt < k2n) {
            half8_t bb = *reinterpret_cast<const half8_t*>(&sTmp[wv][fr * FS + 32 * kt + 8 * fq]);
            acc = __builtin_amdgcn_mfma_f32_16x16x32_f16(afy[kt], bb, acc, 0, 0, 0);
        }
        // C[m = 4*fq + r][n = fr] -> LDS bounce -> coalesced float4 store
        if (fr < 12 && fq < 3) {
            #pragma unroll
            for (int r = 0; r < 4; ++r)
                sOut[wv][(fq * 4 + r) * 12 + fr] = acc[r];
        }
        asm volatile("s_waitcnt lgkmcnt(0)" ::: "memory");
        __builtin_amdgcn_sched_barrier(0);
        if (lane < 36) {
            float4 o = *reinterpret_cast<const float4*>(&sOut[wv][lane * 4]);
            *reinterpret_cast<float4*>(out + (size_t)(2 * b + wv) * 144 + lane * 4) = o;
        }
    }
}

extern "C" void kernel_launch(void* const* d_in, const int* in_sizes, int n_in,
                              void* d_out, int out_size, void* d_ws, size_t ws_size,
                              hipStream_t stream) {
    const float* vec = (const float*)d_in[0];  // (4096,3) f32
    const float* img = (const float*)d_in[1];  // (4096,2,128,128) f32
    float* out = (float*)d_out;                // (4096,2,12,12) f32
    (void)in_sizes; (void)n_in; (void)out_size; (void)d_ws; (void)ws_size;

    glimpse_kernel<<<4096, 256, 0, stream>>>(vec, img, out);
}